// Round 8
// baseline (615.655 us; speedup 1.0000x reference)
//
#include <hip/hip_runtime.h>

#define CC   64
#define SHOT 16
#define DD   320
#define ND   1008            // (CC-1)*SHOT
#define MS   (CC * SHOT)     // 1024
#define LN_EPS 1e-5f

typedef __attribute__((ext_vector_type(8)))  short short8;    // 8 bf16 = 4 VGPR
typedef __attribute__((ext_vector_type(4)))  float floatx4;
typedef __attribute__((ext_vector_type(16))) float floatx16;
typedef __attribute__((ext_vector_type(4)))  int i32x4;

__device__ __forceinline__ unsigned short f2b(float f) {     // fp32 -> bf16 RNE
  union { float f; unsigned int u; } v; v.f = f;
  unsigned int r = v.u + 0x7FFFu + ((v.u >> 16) & 1u);
  return (unsigned short)(r >> 16);
}
__device__ __forceinline__ float b2f(unsigned short b) {
  union { unsigned int u; float f; } v; v.u = ((unsigned int)b) << 16; return v.f;
}
__device__ __forceinline__ unsigned int pk2(float a, float b) {
  return (unsigned int)f2b(a) | ((unsigned int)f2b(b) << 16);
}
__device__ __forceinline__ void gl_lds16(const void* g, void* l) {
  __builtin_amdgcn_global_load_lds(
      (const __attribute__((address_space(1))) unsigned int*)g,
      (__attribute__((address_space(3))) unsigned int*)l, 16, 0, 0);
}
__device__ __forceinline__ floatx4 mfma16(short8 a, short8 b, floatx4 c) {
  return __builtin_amdgcn_mfma_f32_16x16x32_bf16(a, b, c, 0, 0, 0);
}
__device__ __forceinline__ floatx16 mfma32(short8 a, short8 b, floatx16 c) {
  return __builtin_amdgcn_mfma_f32_32x32x16_bf16(a, b, c, 0, 0, 0);
}
#define BARRIER_VM()  do { asm volatile("s_waitcnt vmcnt(0) lgkmcnt(0)" ::: "memory"); \
                           __builtin_amdgcn_s_barrier(); \
                           __builtin_amdgcn_sched_barrier(0); } while (0)

// ---------------------------------------------------------------------------
// MFMA GEMM: Out[M x 320] = A[M x 320] @ W   (Bt = W^T bf16 [320n][320k])
// BM=128 BN=64 BK=64, 4 waves (2x2). mode0: A bf16; mode1: A=xmean[c]-x[gather];
// mode2: A=x[m]-xmean[m/16].  Epilogue: +bias[n], -msMean[(m/msRpc)][n],
// +ResB[m][n] (bf16); writes OutB (bf16 row-major).
// ---------------------------------------------------------------------------
__global__ __launch_bounds__(256, 2) void gemm_mfma(
    const unsigned short* __restrict__ A,
    const float* __restrict__ Xg, const float* __restrict__ Xmean,
    const int mode, const int c0,
    const unsigned short* __restrict__ Bt,
    const float* __restrict__ bias,
    unsigned short* __restrict__ OutB,
    const unsigned short* __restrict__ ResB,
    const float* __restrict__ msMean, const int msRpc)
{
  __shared__ __align__(16) unsigned short As[2][128 * 64];
  __shared__ __align__(16) unsigned short Bs[2][64 * 64];
  const int t  = threadIdx.x;
  const int m0 = blockIdx.x * 128;
  const int n0 = blockIdx.y * 64;
  const int wid = t >> 6, lane = t & 63;
  const int wm = wid >> 1, wn = wid & 1;
  const int l15 = lane & 15, lg = lane >> 4;

  const int ra = t >> 1, kh = t & 1;
  const float* aptr = nullptr; const float* mptr = nullptr;
  if (mode == 1) {
    const int am = m0 + ra;
    const int lc = am / ND, j = am - lc * ND;
    const int c  = c0 + lc;
    const int oi = j >> 4, s = j & 15;
    const int oc = (oi < c) ? oi : oi + 1;
    aptr = Xg + (size_t)(oc * SHOT + s) * DD;
    mptr = Xmean + (size_t)c * DD;
  } else if (mode == 2) {
    aptr = Xg + (size_t)(m0 + ra) * DD;
    mptr = Xmean + (size_t)((m0 + ra) >> 4) * DD;
  }

  floatx4 acc[4][2];
  #pragma unroll
  for (int i = 0; i < 4; ++i)
    #pragma unroll
    for (int j = 0; j < 2; ++j) acc[i][j] = (floatx4){0.f, 0.f, 0.f, 0.f};

  auto stage = [&](int ks, int bufi) {
    const int k0 = ks * 64;
    #pragma unroll
    for (int it = 0; it < 2; ++it) {               // B tile 64x64
      const int L = it * 256 + t;
      const int r = L >> 3, cs = L & 7;
      const int cl = cs ^ (r & 7);
      gl_lds16(Bt + (size_t)(n0 + r) * DD + k0 + cl * 8, &Bs[bufi][0] + L * 8);
    }
    if (mode == 0) {
      #pragma unroll
      for (int it = 0; it < 4; ++it) {             // A tile 128x64
        const int L = it * 256 + t;
        const int r = L >> 3, cs = L & 7;
        const int cl = cs ^ (r & 7);
        gl_lds16(A + (size_t)(m0 + r) * DD + k0 + cl * 8, &As[bufi][0] + L * 8);
      }
    } else {
      const float sa = (mode == 1) ? -1.f : 1.f;
      const int kb2 = k0 + kh * 32;
      #pragma unroll
      for (int i = 0; i < 4; ++i) {
        const float4 x0  = *(const float4*)(aptr + kb2 + i * 8);
        const float4 x1  = *(const float4*)(aptr + kb2 + i * 8 + 4);
        const float4 mv0 = *(const float4*)(mptr + kb2 + i * 8);
        const float4 mv1 = *(const float4*)(mptr + kb2 + i * 8 + 4);
        i32x4 w;
        w[0] = (int)pk2(sa * (x0.x - mv0.x), sa * (x0.y - mv0.y));
        w[1] = (int)pk2(sa * (x0.z - mv0.z), sa * (x0.w - mv0.w));
        w[2] = (int)pk2(sa * (x1.x - mv1.x), sa * (x1.y - mv1.y));
        w[3] = (int)pk2(sa * (x1.z - mv1.z), sa * (x1.w - mv1.w));
        const int c  = kh * 4 + i;
        const int cw = c ^ (ra & 7);
        *(i32x4*)((char*)&As[bufi][0] + ra * 128 + cw * 16) = w;
      }
    }
  };

  auto compute = [&](int bufi) {
    #pragma unroll
    for (int kc = 0; kc < 2; ++kc) {
      short8 af[4], bf[2];
      #pragma unroll
      for (int mt = 0; mt < 4; ++mt) {
        const int row = wm * 64 + mt * 16 + l15;
        const int cs  = (kc * 4 + lg) ^ (row & 7);
        af[mt] = *(const short8*)((const char*)&As[bufi][0] + row * 128 + cs * 16);
      }
      #pragma unroll
      for (int nt = 0; nt < 2; ++nt) {
        const int row = wn * 32 + nt * 16 + l15;
        const int cs  = (kc * 4 + lg) ^ (row & 7);
        bf[nt] = *(const short8*)((const char*)&Bs[bufi][0] + row * 128 + cs * 16);
      }
      #pragma unroll
      for (int mt = 0; mt < 4; ++mt)
        #pragma unroll
        for (int nt = 0; nt < 2; ++nt)
          acc[mt][nt] = mfma16(af[mt], bf[nt], acc[mt][nt]);
    }
  };

  stage(0, 0);
  BARRIER_VM();
  for (int ks = 0; ks < 5; ++ks) {
    if (ks + 1 < 5) stage(ks + 1, (ks + 1) & 1);
    compute(ks & 1);
    BARRIER_VM();
  }

  // epilogue: C[row=(lane>>4)*4+r][col=lane&15]
  #pragma unroll
  for (int nt = 0; nt < 2; ++nt) {
    const int n = n0 + wn * 32 + nt * 16 + l15;
    const float bb = bias[n];
    #pragma unroll
    for (int mt = 0; mt < 4; ++mt) {
      #pragma unroll
      for (int r = 0; r < 4; ++r) {
        const int m = m0 + wm * 64 + mt * 16 + lg * 4 + r;
        float v = acc[mt][nt][r] + bb;
        if (msMean) v -= msMean[(size_t)(m / msRpc) * DD + n];
        if (ResB)   v += b2f(ResB[(size_t)m * DD + n]);
        OutB[(size_t)m * DD + n] = f2b(v);
      }
    }
  }
}

// ---------------------------------------------------------------------------
// 32x32 MFMA flash attention, SINGLE-buffered staging (attn16 loop structure,
// round-3-verified 32x32 compute body). 256 thr / 4 waves x 32 q-rows.
// LDS 41984B (K 20KB + Pt 20KB staging | 2x20992 epilogue overlay) ->
// 2 blocks/CU (VGPR ~252 @ lb(256,1)) = 2 waves/SIMD, no spill.
// Halves LDS-read bytes per q-row vs 16x16 (1.25 vs 2.5 KB/qrow/32kv).
// ---------------------------------------------------------------------------
__global__ __launch_bounds__(256, 1) void attn32(
    const unsigned short* __restrict__ Qg, const unsigned short* __restrict__ Pk,
    const unsigned short* __restrict__ Pt, unsigned short* __restrict__ Ob,
    const int qRows,      // rows per class (Q in + O out): 1008 | 16
    const int kPitch,     // rows per class in Pk: 1008 | 16
    const int vtPitch,    // P^T kv pitch: 1024 | 32
    const int nKT, const int validKV, const int bpc, const int qTiles)
{
  __shared__ __align__(16) char smem[41984];   // staging 40960 | epi 2x20992
  const int t = threadIdx.x;
  const int wid = t >> 6, lane = t & 63;
  const int l31 = lane & 31, hi = lane >> 5;
  const int hi4 = hi * 4, hi8 = hi * 8;

  int bx = blockIdx.x;
  const int nwg = gridDim.x;
  if ((nwg & 7) == 0) bx = (bx & 7) * (nwg >> 3) + (bx >> 3);   // XCD swizzle
  const int cls  = bx / bpc;
  const int blkq = bx - cls * bpc;
  const int qt0 = blkq * 4 + wid;
  const bool wValid = qt0 < qTiles;
  const int qt = wValid ? qt0 : 0;

  // Q fragments (B operand): lane holds Q[q=l31][d = ks*16 + hi*8 + j]
  short8 qf[20];
  {
    const unsigned short* qrow = Qg + ((size_t)cls * qRows + qt * 32 + l31) * DD;
    #pragma unroll
    for (int ks = 0; ks < 20; ++ks) qf[ks] = *(const short8*)(qrow + ks * 16 + hi8);
  }

  floatx16 o[10];
  #pragma unroll
  for (int dt = 0; dt < 10; ++dt) o[dt] = (floatx16)(0.f);
  float mrun = -3.0e38f, lsum = 0.f;
  const float scale = 0.05590169943749474f;   // 1/sqrt(320)

  for (int kt = 0; kt < nKT; ++kt) {
    // ---- stage K = P rows [32 kv][320 d] and V = P^T [320 d][32 kv] ----
    __syncthreads();
    #pragma unroll
    for (int it = 0; it < 5; ++it) {            // K: 1280 16B chunks
      const int L = it * 256 + t;
      const int kv = L / 40, c = L - kv * 40;
      const int g = (c & ~7) | ((c & 7) ^ (kv & 7));
      gl_lds16(Pk + ((size_t)cls * kPitch + kt * 32 + kv) * DD + g * 8, smem + L * 16);
    }
    #pragma unroll
    for (int it = 0; it < 5; ++it) {            // Pt: 1280 16B chunks
      const int L = it * 256 + t;
      const int d = L >> 2, c = L & 3;
      const int g = c ^ ((d >> 1) & 3);
      gl_lds16(Pt + ((size_t)cls * DD + d) * vtPitch + kt * 32 + g * 8,
               smem + 20480 + L * 16);
    }
    __syncthreads();

    // ---- S^T = K @ Q^T (two interleaved chains) ----
    floatx16 sta = (floatx16)(0.f), stb = (floatx16)(0.f);
    __builtin_amdgcn_s_setprio(1);
    #pragma unroll
    for (int ks = 0; ks < 20; ks += 2) {
      const int ca = 2 * ks + hi;
      const int cla = (ca & ~7) | ((ca & 7) ^ (l31 & 7));
      const short8 kfa = *(const short8*)(smem + l31 * 640 + cla * 16);
      sta = mfma32(kfa, qf[ks], sta);
      const int cbx = 2 * (ks + 1) + hi;
      const int clb = (cbx & ~7) | ((cbx & 7) ^ (l31 & 7));
      const short8 kfb = *(const short8*)(smem + l31 * 640 + clb * 16);
      stb = mfma32(kfb, qf[ks + 1], stb);
    }
    __builtin_amdgcn_s_setprio(0);

    // ---- online softmax over 32 kv rows (16 regs + xor-32 partner) ----
    float s[16];
    #pragma unroll
    for (int i = 0; i < 16; ++i) s[i] = (sta[i] + stb[i]) * scale;
    if (kt == nKT - 1) {
      #pragma unroll
      for (int i = 0; i < 16; ++i) {
        const int row = (i & 3) + 8 * (i >> 2) + hi4;
        if (kt * 32 + row >= validKV) s[i] = -1e30f;
      }
    }
    float mt_ = s[0];
    #pragma unroll
    for (int i = 1; i < 16; ++i) mt_ = fmaxf(mt_, s[i]);
    mt_ = fmaxf(mt_, __shfl_xor(mt_, 32));
    if (!__all(mt_ - mrun <= 8.0f)) {           // defer-max (T13)
      const float newm = fmaxf(mrun, mt_);
      const float alpha = __expf(mrun - newm);
      lsum *= alpha;
      #pragma unroll
      for (int dt = 0; dt < 10; ++dt)
        #pragma unroll
        for (int i = 0; i < 16; ++i) o[dt][i] *= alpha;
      mrun = newm;
    }
    float rs = 0.f;
    #pragma unroll
    for (int i = 0; i < 16; ++i) { s[i] = __expf(s[i] - mrun); rs += s[i]; }
    rs += __shfl_xor(rs, 32);
    lsum += rs;

    // ---- pack P -> bf16 PV B-fragments ----
    unsigned int pk[8], ow[8];
    #pragma unroll
    for (int a = 0; a < 8; ++a) pk[a] = pk2(s[2 * a], s[2 * a + 1]);
    #pragma unroll
    for (int a = 0; a < 8; ++a) ow[a] = (unsigned int)__shfl_xor((int)pk[a], 32);
    union { i32x4 w; short8 v; } bf0, bf1;
    bf0.w[0] = (int)(hi ? ow[2] : pk[0]); bf0.w[1] = (int)(hi ? ow[3] : pk[1]);
    bf0.w[2] = (int)(hi ? pk[2] : ow[0]); bf0.w[3] = (int)(hi ? pk[3] : ow[1]);
    bf1.w[0] = (int)(hi ? ow[6] : pk[4]); bf1.w[1] = (int)(hi ? ow[7] : pk[5]);
    bf1.w[2] = (int)(hi ? pk[6] : ow[4]); bf1.w[3] = (int)(hi ? pk[7] : ow[5]);

    // ---- O^T += Pt_tile @ P : 10 d-tiles x 2 k-slices ----
    const char* vb = smem + 20480;
    const int vx = (l31 >> 1) & 3;
    __builtin_amdgcn_s_setprio(1);
    #pragma unroll
    for (int dt = 0; dt < 10; ++dt) {
      const short8 a0 = *(const short8*)(vb + (dt * 32 + l31) * 64 + ((hi ^ vx) << 4));
      o[dt] = mfma32(a0, bf0.v, o[dt]);
    }
    #pragma unroll
    for (int dt = 0; dt < 10; ++dt) {
      const short8 a1 = *(const short8*)(vb + (dt * 32 + l31) * 64 + (((2 + hi) ^ vx) << 4));
      o[dt] = mfma32(a1, bf1.v, o[dt]);
    }
    __builtin_amdgcn_s_setprio(0);
  }

  // ---- epilogue: 2 phases x 2 waves, per-wave LDS [32 q][328 bf16] ----
  const float invl = 1.f / lsum;
  #pragma unroll
  for (int ph = 0; ph < 2; ++ph) {
    __syncthreads();
    if ((wid >> 1) == ph) {
      char* ep = smem + (wid & 1) * 20992;
      #pragma unroll
      for (int dt = 0; dt < 10; ++dt) {
        #pragma unroll
        for (int g = 0; g < 4; ++g) {
          #pragma unroll
          for (int b2 = 0; b2 < 2; ++b2) {
            const int r0 = g * 4 + b2 * 2;
            const unsigned int w = pk2(o[dt][r0] * invl, o[dt][r0 + 1] * invl);
            *(unsigned int*)(ep + l31 * 656 + (dt * 32 + 8 * g + hi4 + 2 * b2) * 2) = w;
          }
        }
      }
    }
    __syncthreads();
    if ((wid >> 1) == ph && wValid) {
      const char* ep = smem + (wid & 1) * 20992;
      #pragma unroll
      for (int it = 0; it < 20; ++it) {
        const int flat = it * 64 + lane;
        const int q = flat / 40, c = flat - (flat / 40) * 40;
        if (qt * 32 + q < qRows) {
          const i32x4 v = *(const i32x4*)(ep + q * 656 + c * 16);
          *(i32x4*)(Ob + ((size_t)cls * qRows + qt * 32 + q) * DD + c * 8) = v;
        }
      }
    }
  }
}

// ---------------------------------------------------------------------------
// P [cls][rowsP][320] bf16 -> Pt [cls][320][vtPitch] bf16, zero-padded kv.
// grid.x = nCls * kvTilesPerCls, grid.y = 5 (64-d tiles). Coalesced both sides.
// ---------------------------------------------------------------------------
__global__ __launch_bounds__(256) void transpose_p(
    const unsigned short* __restrict__ P, unsigned short* __restrict__ PtG,
    const int rowsP, const int vtPitch, const int kvTilesPerCls)
{
  __shared__ __align__(16) unsigned short Ls[64 * 72];
  const int t = threadIdx.x;
  const int cls = blockIdx.x / kvTilesPerCls;
  const int kvt = blockIdx.x - cls * kvTilesPerCls;
  const int dt = blockIdx.y;
  #pragma unroll
  for (int i = 0; i < 2; ++i) {
    const int flat = t + i * 256;
    const int r = flat >> 3, c = flat & 7;
    const int kv = kvt * 64 + r;
    i32x4 v = {0, 0, 0, 0};
    if (kv < rowsP)
      v = *(const i32x4*)(P + ((size_t)cls * rowsP + kv) * DD + dt * 64 + c * 8);
    *(i32x4*)(&Ls[r * 72 + c * 8]) = v;
  }
  __syncthreads();
  #pragma unroll
  for (int i = 0; i < 2; ++i) {
    const int flat = t + i * 256;
    const int r2 = flat >> 3, c2 = flat & 7;
    if (kvt * 64 + c2 * 8 < vtPitch) {
      union { unsigned short e[8]; i32x4 v; } u;
      #pragma unroll
      for (int jj = 0; jj < 8; ++jj) u.e[jj] = Ls[(c2 * 8 + jj) * 72 + r2];
      *(i32x4*)(PtG + ((size_t)cls * DD + dt * 64 + r2) * vtPitch + kvt * 64 + c2 * 8) = u.v;
    }
  }
}

// ---------------------------------------------------------------------------
// W [320k][320n] fp32 -> Wt [320n][320k] bf16
// ---------------------------------------------------------------------------
__global__ __launch_bounds__(256) void transpose_w(const float* __restrict__ W,
                                                   unsigned short* __restrict__ Wt)
{
  __shared__ float Ls[64][68];
  const int t = threadIdx.x;
  const int k0 = blockIdx.x * 64, n0 = blockIdx.y * 64;
  #pragma unroll
  for (int i = 0; i < 4; ++i) {
    const int flat = t + i * 256;
    const int r = flat >> 4, c = (flat & 15) * 4;
    *(float4*)&Ls[r][c] = *(const float4*)(W + (size_t)(k0 + r) * DD + n0 + c);
  }
  __syncthreads();
  #pragma unroll
  for (int j = 0; j < 2; ++j) {
    const int flat = t + j * 256;
    const int r2 = flat >> 3, c2 = flat & 7;
    union { unsigned short e[8]; i32x4 v; } u;
    #pragma unroll
    for (int jj = 0; jj < 8; ++jj) u.e[jj] = f2b(Ls[c2 * 8 + jj][r2]);
    *(i32x4*)(Wt + (size_t)(n0 + r2) * DD + k0 + c2 * 8) = u.v;
  }
}

// ---------------------------------------------------------------------------
// Weight product: Bt[n][k] = sum_m L'[n][m] * R[k][m], L'[n][m] = trL?L[m][n]:L[n][m]
// ---------------------------------------------------------------------------
__global__ __launch_bounds__(256) void wprod(const float* __restrict__ L,
                                             const float* __restrict__ R,
                                             const int trL,
                                             unsigned short* __restrict__ Bt)
{
  __shared__ float Lsm[16][68];
  __shared__ float Rsm[16][68];
  const int t = threadIdx.x;
  const int n0 = blockIdx.x * 64, k0 = blockIdx.y * 64;
  const int tn4 = (t & 15) * 4, tk4 = (t >> 4) * 4;
  float acc[4][4] = {};
  for (int ms = 0; ms < DD; ms += 16) {
    const int lr = t >> 4, lc = (t & 15);
    #pragma unroll
    for (int i = 0; i < 4; ++i) {
      const int nn = lc * 4 + i;
      Lsm[lr][nn] = trL ? L[(size_t)(ms + lr) * DD + n0 + nn]
                        : L[(size_t)(n0 + nn) * DD + ms + lr];
      Rsm[lr][nn] = R[(size_t)(k0 + nn) * DD + ms + lr];
    }
    __syncthreads();
    #pragma unroll
    for (int mm = 0; mm < 16; ++mm) {
      float la[4], rb[4];
      #pragma unroll
      for (int i = 0; i < 4; ++i) { la[i] = Lsm[mm][tn4 + i]; rb[i] = Rsm[mm][tk4 + i]; }
      #pragma unroll
      for (int i = 0; i < 4; ++i)
        #pragma unroll
        for (int j = 0; j < 4; ++j) acc[i][j] += la[i] * rb[j];
    }
    __syncthreads();
  }
  #pragma unroll
  for (int i = 0; i < 4; ++i)
    #pragma unroll
    for (int j = 0; j < 4; ++j)
      Bt[(size_t)(n0 + tn4 + i) * DD + k0 + tk4 + j] = f2b(acc[i][j]);
}

// v[n] = sum_m Wk[n,m] bq[m];  bvf[n] = sum_m Wfc[m,n] bv[m] + bfc[n]
__global__ __launch_bounds__(640) void wbias(
    const float* __restrict__ Wk, const float* __restrict__ bq,
    const float* __restrict__ Wfc, const float* __restrict__ bv,
    const float* __restrict__ bfc, float* __restrict__ v, float* __restrict__ bvf)
{
  const int t = threadIdx.x;
  if (t < DD) {
    float a = 0.f;
    for (int m = 0; m < DD; ++m) a += Wk[(size_t)t * DD + m] * bq[m];
    v[t] = a;
  } else if (t < 2 * DD) {
    const int n = t - DD;
    float a = 0.f;
    for (int m = 0; m < DD; ++m) a += Wfc[(size_t)m * DD + n] * bv[m];
    bvf[n] = a + bfc[n];
  }
}

// ---------------------------------------------------------------------------
// Per-row LayerNorm + logit (bf16 in), 1 wave/row.
// ---------------------------------------------------------------------------
__global__ __launch_bounds__(256) void ln_logit(
    const unsigned short* __restrict__ X, const float* __restrict__ gam,
    const float* __restrict__ bet, const float* __restrict__ Wout,
    const float* __restrict__ bout, float* __restrict__ logits, const int M)
{
  const int row = blockIdx.x * 4 + (threadIdx.x >> 6);
  if (row >= M) return;
  const int lane = threadIdx.x & 63;
  const unsigned short* x = X + (size_t)row * DD;
  float v[5]; float s = 0.f;
  #pragma unroll
  for (int i = 0; i < 5; ++i) { v[i] = b2f(x[lane + 64 * i]); s += v[i]; }
  #pragma unroll
  for (int off = 32; off; off >>= 1) s += __shfl_xor(s, off);
  const float mu = s * (1.f / DD);
  float q = 0.f;
  #pragma unroll
  for (int i = 0; i < 5; ++i) { const float d = v[i] - mu; q += d * d; }
  #pragma unroll
  for (int off = 32; off; off >>= 1) q += __shfl_xor(q, off);
  const float inv = rsqrtf(q * (1.f / DD) + LN_EPS);
  float lg = 0.f;
  #pragma unroll
  for (int i = 0; i < 5; ++i) {
    const int k = lane + 64 * i;
    lg += (gam[k] * (v[i] - mu) * inv + bet[k]) * Wout[k];
  }
  #pragma unroll
  for (int off = 32; off; off >>= 1) lg += __shfl_xor(lg, off);
  if (lane == 0) logits[row] = lg + bout[0];
}

// ---------------------------------------------------------------------------
// Final: per-class softmax over logits, weighted mean of P (bf16).
// ---------------------------------------------------------------------------
__global__ __launch_bounds__(320) void final_reduce(
    const float* __restrict__ logits_s, const float* __restrict__ logits_d,
    const unsigned short* __restrict__ Ps, const unsigned short* __restrict__ Pd,
    float* __restrict__ out)
{
  const int c = blockIdx.x;
  const int t = threadIdx.x;
  __shared__ float w[16 + ND];
  __shared__ float red[5];
  if (t < 16) w[t] = logits_s[c * 16 + t];
  for (int j = t; j < ND; j += 320) w[16 + j] = logits_d[c * ND + j];
  __syncthreads();
  if (t == 0) {
    float mx = w[0];
    #pragma unroll
    for (int i = 1; i < 16; ++i) mx = fmaxf(mx, w[i]);
    float ssum = 0.f;
    #pragma unroll
    for (int i = 0; i < 16; ++i) { const float e = __expf(w[i] - mx); w[i] = e; ssum += e; }
    const float inv = 1.f / ssum;
    #pragma unroll
    for (int i = 0; i < 16; ++i) w[i] *= inv;
  }
  float lm = -1e30f;
  for (int j = t; j < ND; j += 320) lm = fmaxf(lm, w[16 + j]);
  #pragma unroll
  for (int off = 32; off; off >>= 1) lm = fmaxf(lm, __shfl_xor(lm, off));
  if ((t & 63) == 0) red[t >> 6] = lm;
  __syncthreads();
  const float mx = fmaxf(fmaxf(fmaxf(red[0], red[1]), fmaxf(red[2], red[3])), red[4]);
  float ls = 0.f;
  for (int j = t; j < ND; j += 320) { const float e = __expf(w[16 + j] - mx); w[16 + j] = e; ls += e; }
  #pragma unroll
  for (int off = 32; off; off >>= 1) ls += __shfl_xor(ls, off);
  __syncthreads();
  if ((t & 63) == 0) red[t >> 6] = ls;
  __syncthreads();
  const float inv = 1.f / (red[0] + red[1] + red[2] + red[3] + red[4]);
  for (int j = t; j < ND; j += 320) w[16 + j] *= inv;
  __syncthreads();
  float acc = 0.f;
  const unsigned short* Psc = Ps + (size_t)c * SHOT * DD + t;
  const unsigned short* Pdc = Pd + (size_t)c * ND * DD + t;
  #pragma unroll 4
  for (int i = 0; i < 16; ++i) acc += w[i] * b2f(Psc[(size_t)i * DD]);
  for (int j = 0; j < ND; ++j) acc += w[16 + j] * b2f(Pdc[(size_t)j * DD]);
  out[c * DD + t] = acc * (1.f / 1024.f);
}

// ---------------------------------------------------------------------------
extern "C" void kernel_launch(void* const* d_in, const int* in_sizes, int n_in,
                              void* d_out, int out_size, void* d_ws, size_t ws_size,
                              hipStream_t stream)
{
  const float* xmean = (const float*)d_in[0];
  const float* x     = (const float*)d_in[1];
  const float* Wsame = (const float*)d_in[2];
  const float* bsame = (const float*)d_in[3];
  const float* Wdiff = (const float*)d_in[4];
  const float* bdiff = (const float*)d_in[5];
  const float* Wq    = (const float*)d_in[6];
  const float* bq    = (const float*)d_in[7];
  const float* Wk    = (const float*)d_in[8];
  const float* bk    = (const float*)d_in[9];   (void)bk; // row-const in softmax
  const float* Wv    = (const float*)d_in[10];
  const float* bv    = (const float*)d_in[11];
  const float* Wfc   = (const float*)d_in[12];
  const float* bfc   = (const float*)d_in[13];
  const float* lng   = (const float*)d_in[14];
  const float* lnb   = (const float*)d_in[15];
  const float* Wout  = (const float*)d_in[16];
  const float* boutp = (const float*)d_in[17];
  float* outp = (float*)d_out;

  char* base = (char*)d_ws;
  size_t off = 0;
  auto alloc = [&](size_t bytes) { char* p = base + off; off += (bytes + 255) & ~(size_t)255; return p; };

  const size_t WB = (size_t)DD * DD * 2;
  unsigned short* BtS  = (unsigned short*)alloc(WB);
  unsigned short* BtD  = (unsigned short*)alloc(WB);
  unsigned short* BtG  = (unsigned short*)alloc(WB);
  unsigned short* BtVF = (unsigned short*)alloc(WB);
  float* vbias = (float*)alloc(DD * 4);
  float* bvf   = (float*)alloc(DD * 4);
  unsigned short* Pd_b = (unsigned short*)alloc((size_t)(CC * ND + 64) * DD * 2);
  unsigned short* Ps_b = (unsigned short*)alloc((size_t)(MS + 64) * DD * 2);
  unsigned short* PtS  = (unsigned short*)alloc((size_t)CC * DD * 32 * 2);
  unsigned short* Qgs  = (unsigned short*)alloc((size_t)(MS + 64) * DD * 2);  // also F_same
  unsigned short* Os_b = (unsigned short*)alloc((size_t)MS * DD * 2);
  float* logs = (float*)alloc((size_t)MS * 4);
  float* logd = (float*)alloc((size_t)CC * ND * 4);

  // class-chunk the diff branch; CB in {64,32,16,8}
  int CB = 64;
  while (CB > 8) {
    size_t need = off;
    need += ((size_t)CB * DD * 1024 * 2 + 255 & ~(size_t)255);          // PtD
    need += ((size_t)(CB * ND + 64) * DD * 2 + 255 & ~(size_t)255);     // Qgd (=F)
    need += ((size_t)CB * ND * DD * 2 + 255 & ~(size_t)255);            // Od
    if (need <= ws_size) break;
    CB >>= 1;
  }
  unsigned short* PtD = (unsigned short*)alloc((size_t)CB * DD * 1024 * 2);
  unsigned short* Qgd = (unsigned short*)alloc((size_t)(CB * ND + 64) * DD * 2);
  unsigned short* Od  = (unsigned short*)alloc((size_t)CB * ND * DD * 2);

  const dim3 blk(256);
  // ---- weight prep ----
  transpose_w<<<dim3(5, 5), blk, 0, stream>>>(Wsame, BtS);
  transpose_w<<<dim3(5, 5), blk, 0, stream>>>(Wdiff, BtD);
  wprod<<<dim3(5, 5), blk, 0, stream>>>(Wk, Wq, 0, BtG);    // (Wq Wk^T)^T
  wprod<<<dim3(5, 5), blk, 0, stream>>>(Wfc, Wv, 1, BtVF);  // (Wv Wfc)^T
  wbias<<<dim3(1), dim3(640), 0, stream>>>(Wk, bq, Wfc, bv, bfc, vbias, bvf);

  // ---- same branch ----
  {
    const dim3 g(MS / 128, 5);
    gemm_mfma<<<g, blk, 0, stream>>>(nullptr, x, xmean, 2, 0, BtS, bsame,
                                     Ps_b, nullptr, xmean, 16);
    transpose_p<<<dim3(CC, 5), blk, 0, stream>>>(Ps_b, PtS, 16, 32, 1);
    gemm_mfma<<<g, blk, 0, stream>>>(Ps_b, nullptr, nullptr, 0, 0, BtG, vbias,
                                     Qgs, nullptr, nullptr, 1);
    attn32<<<dim3(CC), blk, 0, stream>>>(Qgs, Ps_b, PtS, Os_b,
                                         16, 16, 32, 1, 16, 1, 1);
    gemm_mfma<<<g, blk, 0, stream>>>(Os_b, nullptr, nullptr, 0, 0, BtVF, bvf,
                                     Qgs, Ps_b, nullptr, 1);
    ln_logit<<<dim3(MS / 4), blk, 0, stream>>>(Qgs, lng, lnb, Wout, boutp, logs, MS);
  }

  // ---- diff branch, chunked ----
  for (int c0 = 0; c0 < CC; c0 += CB) {
    const int Mch = CB * ND;
    unsigned short* Pch = Pd_b + (size_t)c0 * ND * DD;
    const dim3 g(Mch / 128, 5);
    gemm_mfma<<<g, blk, 0, stream>>>(nullptr, x, xmean, 1, c0, BtD, bdiff,
                                     Pch, nullptr, xmean + (size_t)c0 * DD, ND);
    transpose_p<<<dim3(CB * 16, 5), blk, 0, stream>>>(Pch, PtD, ND, 1024, 16);
    gemm_mfma<<<g, blk, 0, stream>>>(Pch, nullptr, nullptr, 0, 0, BtG, vbias,
                                     Qgd, nullptr, nullptr, 1);
    attn32<<<dim3(CB * 8), blk, 0, stream>>>(Qgd, Pch, PtD, Od,
                                             ND, ND, 1024, 32, ND, 8, 32);
    gemm_mfma<<<g, blk, 0, stream>>>(Od, nullptr, nullptr, 0, 0, BtVF, bvf,
                                     Qgd, Pch, nullptr, 1);
    ln_logit<<<dim3(Mch / 4), blk, 0, stream>>>(Qgd, lng, lnb, Wout, boutp,
                                                logd + (size_t)c0 * ND, Mch);
  }

  final_reduce<<<dim3(CC), dim3(320), 0, stream>>>(logs, logd, Ps_b, Pd_b, outp);
}

// Round 9
// 488.200 us; speedup vs baseline: 1.2611x; 1.2611x over previous
//
#include <hip/hip_runtime.h>

#define CC   64
#define SHOT 16
#define DD   320
#define ND   1008            // (CC-1)*SHOT
#define MS   (CC * SHOT)     // 1024
#define MD   (CC * ND)       // 64512
#define MT   (MD + MS)       // 65536 = 512*128
#define LN_EPS 1e-5f

typedef __attribute__((ext_vector_type(8)))  short short8;    // 8 bf16 = 4 VGPR
typedef __attribute__((ext_vector_type(4)))  float floatx4;
typedef __attribute__((ext_vector_type(4)))  int i32x4;

__device__ __forceinline__ unsigned short f2b(float f) {     // fp32 -> bf16 RNE
  union { float f; unsigned int u; } v; v.f = f;
  unsigned int r = v.u + 0x7FFFu + ((v.u >> 16) & 1u);
  return (unsigned short)(r >> 16);
}
__device__ __forceinline__ float b2f(unsigned short b) {
  union { unsigned int u; float f; } v; v.u = ((unsigned int)b) << 16; return v.f;
}
__device__ __forceinline__ unsigned int pk2(float a, float b) {
  return (unsigned int)f2b(a) | ((unsigned int)f2b(b) << 16);
}
__device__ __forceinline__ void gl_lds16(const void* g, void* l) {
  __builtin_amdgcn_global_load_lds(
      (const __attribute__((address_space(1))) unsigned int*)g,
      (__attribute__((address_space(3))) unsigned int*)l, 16, 0, 0);
}
__device__ __forceinline__ floatx4 mfma16(short8 a, short8 b, floatx4 c) {
  return __builtin_amdgcn_mfma_f32_16x16x32_bf16(a, b, c, 0, 0, 0);
}
#define BARRIER_VM()  do { asm volatile("s_waitcnt vmcnt(0) lgkmcnt(0)" ::: "memory"); \
                           __builtin_amdgcn_s_barrier(); \
                           __builtin_amdgcn_sched_barrier(0); } while (0)

// ---------------------------------------------------------------------------
// MFMA GEMM over the MERGED row space [0,65536): rows <MD are diff-branch,
// rows >=MD are same-branch. BM=128 BN=64 BK=64, 4 waves (2x2).
// mode 0: A bf16 passthrough, weights BtDiff/biasDiff for ALL rows,
//         optional residual ResB, no mean-sub.
// mode 3: P-build. Per-block region select (blocks are region-pure since
//         MD%128==0): diff: A=xmean[c]-x[gather], W=BtDiff,b=biasDiff;
//         same: A=x[ls]-xmean[ls/16], W=BtSame,b=biasSame. Epilogue subtracts
//         xmean[class][n] for both regions.
// ---------------------------------------------------------------------------
__global__ __launch_bounds__(256, 2) void gemm_mfma(
    const unsigned short* __restrict__ A,
    const float* __restrict__ Xg, const float* __restrict__ Xmean,
    const int mode,
    const unsigned short* __restrict__ BtDiff,
    const unsigned short* __restrict__ BtSame,
    const float* __restrict__ biasDiff, const float* __restrict__ biasSame,
    unsigned short* __restrict__ OutB,
    const unsigned short* __restrict__ ResB)
{
  __shared__ __align__(16) unsigned short As[2][128 * 64];
  __shared__ __align__(16) unsigned short Bs[2][64 * 64];
  const int t  = threadIdx.x;
  const int m0 = blockIdx.x * 128;
  const int n0 = blockIdx.y * 64;
  const int wid = t >> 6, lane = t & 63;
  const int wm = wid >> 1, wn = wid & 1;
  const int l15 = lane & 15, lg = lane >> 4;

  const bool isDiff = (m0 < MD);
  const unsigned short* Bt = (mode == 3 && !isDiff) ? BtSame : BtDiff;
  const float* bias = (mode == 3 && !isDiff) ? biasSame : biasDiff;

  const int ra = t >> 1, kh = t & 1;
  const float* aptr = nullptr; const float* mptr = nullptr;
  float sa = 1.f;
  if (mode == 3) {
    const int am = m0 + ra;
    if (isDiff) {
      const int c = am / ND, j = am - c * ND;
      const int oi = j >> 4, s = j & 15;
      const int oc = (oi < c) ? oi : oi + 1;
      aptr = Xg + (size_t)(oc * SHOT + s) * DD;
      mptr = Xmean + (size_t)c * DD;
      sa = -1.f;
    } else {
      const int ls = am - MD;
      aptr = Xg + (size_t)ls * DD;
      mptr = Xmean + (size_t)(ls >> 4) * DD;
      sa = 1.f;
    }
  }

  floatx4 acc[4][2];
  #pragma unroll
  for (int i = 0; i < 4; ++i)
    #pragma unroll
    for (int j = 0; j < 2; ++j) acc[i][j] = (floatx4){0.f, 0.f, 0.f, 0.f};

  auto stage = [&](int ks, int bufi) {
    const int k0 = ks * 64;
    #pragma unroll
    for (int it = 0; it < 2; ++it) {               // B tile 64x64
      const int L = it * 256 + t;
      const int r = L >> 3, cs = L & 7;
      const int cl = cs ^ (r & 7);
      gl_lds16(Bt + (size_t)(n0 + r) * DD + k0 + cl * 8, &Bs[bufi][0] + L * 8);
    }
    if (mode == 0) {
      #pragma unroll
      for (int it = 0; it < 4; ++it) {             // A tile 128x64
        const int L = it * 256 + t;
        const int r = L >> 3, cs = L & 7;
        const int cl = cs ^ (r & 7);
        gl_lds16(A + (size_t)(m0 + r) * DD + k0 + cl * 8, &As[bufi][0] + L * 8);
      }
    } else {                                        // fp32 gather+sub+cvt
      const int kb2 = k0 + kh * 32;
      #pragma unroll
      for (int i = 0; i < 4; ++i) {
        const float4 x0  = *(const float4*)(aptr + kb2 + i * 8);
        const float4 x1  = *(const float4*)(aptr + kb2 + i * 8 + 4);
        const float4 mv0 = *(const float4*)(mptr + kb2 + i * 8);
        const float4 mv1 = *(const float4*)(mptr + kb2 + i * 8 + 4);
        i32x4 w;
        w[0] = (int)pk2(sa * (x0.x - mv0.x), sa * (x0.y - mv0.y));
        w[1] = (int)pk2(sa * (x0.z - mv0.z), sa * (x0.w - mv0.w));
        w[2] = (int)pk2(sa * (x1.x - mv1.x), sa * (x1.y - mv1.y));
        w[3] = (int)pk2(sa * (x1.z - mv1.z), sa * (x1.w - mv1.w));
        const int c  = kh * 4 + i;
        const int cw = c ^ (ra & 7);
        *(i32x4*)((char*)&As[bufi][0] + ra * 128 + cw * 16) = w;
      }
    }
  };

  auto compute = [&](int bufi) {
    #pragma unroll
    for (int kc = 0; kc < 2; ++kc) {
      short8 af[4], bf[2];
      #pragma unroll
      for (int mt = 0; mt < 4; ++mt) {
        const int row = wm * 64 + mt * 16 + l15;
        const int cs  = (kc * 4 + lg) ^ (row & 7);
        af[mt] = *(const short8*)((const char*)&As[bufi][0] + row * 128 + cs * 16);
      }
      #pragma unroll
      for (int nt = 0; nt < 2; ++nt) {
        const int row = wn * 32 + nt * 16 + l15;
        const int cs  = (kc * 4 + lg) ^ (row & 7);
        bf[nt] = *(const short8*)((const char*)&Bs[bufi][0] + row * 128 + cs * 16);
      }
      #pragma unroll
      for (int mt = 0; mt < 4; ++mt)
        #pragma unroll
        for (int nt = 0; nt < 2; ++nt)
          acc[mt][nt] = mfma16(af[mt], bf[nt], acc[mt][nt]);
    }
  };

  stage(0, 0);
  BARRIER_VM();
  for (int ks = 0; ks < 5; ++ks) {
    if (ks + 1 < 5) stage(ks + 1, (ks + 1) & 1);
    compute(ks & 1);
    BARRIER_VM();
  }

  // epilogue: C[row=(lane>>4)*4+r][col=lane&15]
  #pragma unroll
  for (int nt = 0; nt < 2; ++nt) {
    const int n = n0 + wn * 32 + nt * 16 + l15;
    const float bb = bias[n];
    #pragma unroll
    for (int mt = 0; mt < 4; ++mt) {
      #pragma unroll
      for (int r = 0; r < 4; ++r) {
        const int m = m0 + wm * 64 + mt * 16 + lg * 4 + r;
        float v = acc[mt][nt][r] + bb;
        if (mode == 3) {
          const int cm = isDiff ? (m / ND) : ((m - MD) >> 4);
          v -= Xmean[(size_t)cm * DD + n];
        }
        if (ResB) v += b2f(ResB[(size_t)m * DD + n]);
        OutB[(size_t)m * DD + n] = f2b(v);
      }
    }
  }
}

// ---------------------------------------------------------------------------
// 16x16 MFMA flash attention (round-7 proven: 162us diff). 256 thr / 4 waves
// x 16 q-rows, kv-tile 32, single-buffered K/Pt staging (41KB -> 3 blk/CU).
// K-operand = P rows; V-operand = P^T. Swapped QK^T; skip-rescale; in-reg P
// pack via 8 shfl; O^T = mfma16(Pt_frag, P_frag); setprio on MFMA clusters.
// ---------------------------------------------------------------------------
__global__ __launch_bounds__(256, 2) void attn16(
    const unsigned short* __restrict__ Qg, const unsigned short* __restrict__ Pk,
    const unsigned short* __restrict__ Pt, unsigned short* __restrict__ Ob,
    const int qRows,      // rows per class: 1008 | 16
    const int kPitch,     // rows per class in Pk: 1008 | 16
    const int vtPitch,    // P^T kv pitch: 1024 | 32
    const int nKT, const int validKV, const int bpc, const int qTiles)
{
  __shared__ __align__(16) char smem[64 * 656];   // 41984B: staging 40960 | epi 4x10496
  const int t = threadIdx.x;
  const int wid = t >> 6, lane = t & 63;
  const int l15 = lane & 15, lg = lane >> 4;

  int bx = blockIdx.x;
  const int nwg = gridDim.x;
  if ((nwg & 7) == 0) bx = (bx & 7) * (nwg >> 3) + (bx >> 3);   // XCD swizzle
  const int cls  = bx / bpc;
  const int blkq = bx - cls * bpc;
  const int qt0 = blkq * 4 + wid;
  const bool wValid = qt0 < qTiles;
  const int qt = wValid ? qt0 : qTiles - 1;

  // Q fragments (B operand): lane holds Q[q=l15][kd = kc*32 + lg*8 + j]
  short8 qf[10];
  {
    const unsigned short* qrow = Qg + ((size_t)cls * qRows + qt * 16 + l15) * DD;
    #pragma unroll
    for (int kc = 0; kc < 10; ++kc) qf[kc] = *(const short8*)(qrow + kc * 32 + lg * 8);
  }

  floatx4 o[20];
  #pragma unroll
  for (int i = 0; i < 20; ++i) o[i] = (floatx4){0.f, 0.f, 0.f, 0.f};
  float mrun = -1e30f, lsum = 0.f;
  const float scale = 0.05590169943749474f;       // 1/sqrt(320)

  for (int kt = 0; kt < nKT; ++kt) {
    // ---- stage K = P rows [32 kv][320 d] and V = P^T [320 d][32 kv] ----
    __syncthreads();
    #pragma unroll
    for (int it = 0; it < 5; ++it) {
      const int L = it * 256 + t;                 // 16B chunk
      const int r = L / 40, c = L - (L / 40) * 40;
      const int cl = (c & ~7) | ((c & 7) ^ (r & 7));
      gl_lds16(Pk + ((size_t)cls * kPitch + kt * 32 + r) * DD + cl * 8, smem + L * 16);
    }
    #pragma unroll
    for (int it = 0; it < 5; ++it) {
      const int L = it * 256 + t;
      const int d = L >> 2, c = L & 3;
      const int cl = c ^ ((d >> 1) & 3);
      gl_lds16(Pt + ((size_t)cls * DD + d) * vtPitch + kt * 32 + cl * 8,
               smem + 20480 + L * 16);
    }
    __syncthreads();

    // ---- S^T = K @ Q^T : lane holds St[kv=st*16+lg*4+r][q=l15] ----
    floatx4 st0 = (floatx4){0.f,0.f,0.f,0.f}, st1 = (floatx4){0.f,0.f,0.f,0.f};
    __builtin_amdgcn_s_setprio(1);
    #pragma unroll
    for (int kc = 0; kc < 10; ++kc) {
      const int c = kc * 4 + lg;
      const int cl = (c & ~7) | ((c & 7) ^ (l15 & 7));
      const short8 k0f = *(const short8*)(smem + l15 * 640 + cl * 16);
      const short8 k1f = *(const short8*)(smem + (16 + l15) * 640 + cl * 16);
      st0 = mfma16(k0f, qf[kc], st0);
      st1 = mfma16(k1f, qf[kc], st1);
    }
    __builtin_amdgcn_s_setprio(0);

    // ---- online softmax ----
    float s[8];
    #pragma unroll
    for (int r = 0; r < 4; ++r) { s[r] = st0[r] * scale; s[4 + r] = st1[r] * scale; }
    const int kvb = kt * 32 + lg * 4;
    #pragma unroll
    for (int r = 0; r < 4; ++r) {
      if (kvb + r      >= validKV) s[r]     = -1e30f;
      if (kvb + 16 + r >= validKV) s[4 + r] = -1e30f;
    }
    float mt_ = s[0];
    #pragma unroll
    for (int i = 1; i < 8; ++i) mt_ = fmaxf(mt_, s[i]);
    mt_ = fmaxf(mt_, __shfl_xor(mt_, 16));
    mt_ = fmaxf(mt_, __shfl_xor(mt_, 32));
    const float newm = fmaxf(mrun, mt_);
    if (__any(newm > mrun)) {                     // skip-rescale when no new max
      const float alpha = __expf(mrun - newm);
      lsum *= alpha;
      #pragma unroll
      for (int i = 0; i < 20; ++i) {
        o[i][0] *= alpha; o[i][1] *= alpha; o[i][2] *= alpha; o[i][3] *= alpha;
      }
      mrun = newm;
    }
    float p[8]; float rs = 0.f;
    #pragma unroll
    for (int i = 0; i < 8; ++i) { p[i] = __expf(s[i] - mrun); rs += p[i]; }
    rs += __shfl_xor(rs, 16);
    rs += __shfl_xor(rs, 32);
    lsum += rs;

    // ---- pack P to bf16, redistribute to PV B-frag ----
    const unsigned int pk00 = pk2(p[0], p[1]), pk01 = pk2(p[2], p[3]);
    const unsigned int pk10 = pk2(p[4], p[5]), pk11 = pk2(p[6], p[7]);
    const int src0 = l15 + ((lane >> 4) & 1) * 32;
    const int src1 = src0 + 16;
    const int y0 = __shfl((int)pk00, src0), y1 = __shfl((int)pk01, src0);
    const int y2 = __shfl((int)pk00, src1), y3 = __shfl((int)pk01, src1);
    const int z0 = __shfl((int)pk10, src0), z1 = __shfl((int)pk11, src0);
    const int z2 = __shfl((int)pk10, src1), z3 = __shfl((int)pk11, src1);
    const bool hi = lane >= 32;                   // subtile select (kv>=16)
    union { i32x4 w; short8 v; } pf;
    pf.w[0] = hi ? z0 : y0; pf.w[1] = hi ? z1 : y1;
    pf.w[2] = hi ? z2 : y2; pf.w[3] = hi ? z3 : y3;

    // ---- O^T += Pt_tile @ P : 20 d-tiles ----
    const int vswz = (l15 >> 1) & 3;
    __builtin_amdgcn_s_setprio(1);
    #pragma unroll
    for (int dt = 0; dt < 20; ++dt) {
      const int d = dt * 16 + l15;
      const short8 a = *(const short8*)(smem + 20480 + d * 64 + ((lg ^ vswz) << 4));
      o[dt] = mfma16(a, pf.v, o[dt]);
    }
    __builtin_amdgcn_s_setprio(0);
  }

  // ---- epilogue: O^T frags -> per-wave LDS [16q][328 bf16] -> coalesced ----
  const float invl = 1.f / lsum;
  __syncthreads();
  char* ep = smem + wid * 10496;
  #pragma unroll
  for (int dt = 0; dt < 20; ++dt) {
    const unsigned int w0 = pk2(o[dt][0] * invl, o[dt][1] * invl);
    const unsigned int w1 = pk2(o[dt][2] * invl, o[dt][3] * invl);
    *(unsigned int*)(ep + l15 * 656 + (dt * 16 + lg * 4) * 2)     = w0;
    *(unsigned int*)(ep + l15 * 656 + (dt * 16 + lg * 4 + 2) * 2) = w1;
  }
  __syncthreads();
  if (wValid) {
    #pragma unroll
    for (int it = 0; it < 10; ++it) {
      const int flat = it * 64 + lane;
      const int q = flat / 40, c = flat - (flat / 40) * 40;
      const i32x4 v = *(const i32x4*)(ep + q * 656 + c * 16);
      *(i32x4*)(Ob + ((size_t)cls * qRows + qt * 16 + q) * DD + c * 8) = v;
    }
  }
}

// ---------------------------------------------------------------------------
// P [cls][rowsP][320] bf16 -> Pt [cls][320][vtPitch] bf16, zero-padded kv.
// ---------------------------------------------------------------------------
__global__ __launch_bounds__(256) void transpose_p(
    const unsigned short* __restrict__ P, unsigned short* __restrict__ PtG,
    const int rowsP, const int vtPitch, const int kvTilesPerCls)
{
  __shared__ __align__(16) unsigned short Ls[64 * 72];
  const int t = threadIdx.x;
  const int cls = blockIdx.x / kvTilesPerCls;
  const int kvt = blockIdx.x - cls * kvTilesPerCls;
  const int dt = blockIdx.y;
  #pragma unroll
  for (int i = 0; i < 2; ++i) {
    const int flat = t + i * 256;
    const int r = flat >> 3, c = flat & 7;
    const int kv = kvt * 64 + r;
    i32x4 v = {0, 0, 0, 0};
    if (kv < rowsP)
      v = *(const i32x4*)(P + ((size_t)cls * rowsP + kv) * DD + dt * 64 + c * 8);
    *(i32x4*)(&Ls[r * 72 + c * 8]) = v;
  }
  __syncthreads();
  #pragma unroll
  for (int i = 0; i < 2; ++i) {
    const int flat = t + i * 256;
    const int r2 = flat >> 3, c2 = flat & 7;
    if (kvt * 64 + c2 * 8 < vtPitch) {
      union { unsigned short e[8]; i32x4 v; } u;
      #pragma unroll
      for (int jj = 0; jj < 8; ++jj) u.e[jj] = Ls[(c2 * 8 + jj) * 72 + r2];
      *(i32x4*)(PtG + ((size_t)cls * DD + dt * 64 + r2) * vtPitch + kvt * 64 + c2 * 8) = u.v;
    }
  }
}

// ---------------------------------------------------------------------------
// Merged weight prep (grid.z selects task):
//  z=0: BtS = (Wsame)^T bf16   z=1: BtD = (Wdiff)^T bf16
//  z=2: BtG[n][k] = sum_m Wk[n,m] Wq[k,m]   z=3: BtVF[n][k] = sum_m Wfc[m,n] Wv[k,m]
// ---------------------------------------------------------------------------
__global__ __launch_bounds__(256) void wprep(
    const float* __restrict__ Wsame, const float* __restrict__ Wdiff,
    const float* __restrict__ Wk, const float* __restrict__ Wq,
    const float* __restrict__ Wfc, const float* __restrict__ Wv,
    unsigned short* __restrict__ BtS, unsigned short* __restrict__ BtD,
    unsigned short* __restrict__ BtG, unsigned short* __restrict__ BtVF)
{
  __shared__ float Ls[64 * 68];
  const int t = threadIdx.x;
  const int z = blockIdx.z;
  if (z < 2) {                                   // transpose fp32 -> bf16^T
    const float* W = z ? Wdiff : Wsame;
    unsigned short* Wt = z ? BtD : BtS;
    const int k0 = blockIdx.x * 64, n0 = blockIdx.y * 64;
    #pragma unroll
    for (int i = 0; i < 4; ++i) {
      const int flat = t + i * 256;
      const int r = flat >> 4, c = (flat & 15) * 4;
      *(float4*)&Ls[r * 68 + c] = *(const float4*)(W + (size_t)(k0 + r) * DD + n0 + c);
    }
    __syncthreads();
    #pragma unroll
    for (int j = 0; j < 2; ++j) {
      const int flat = t + j * 256;
      const int r2 = flat >> 3, c2 = flat & 7;
      union { unsigned short e[8]; i32x4 v; } u;
      #pragma unroll
      for (int jj = 0; jj < 8; ++jj) u.e[jj] = f2b(Ls[(c2 * 8 + jj) * 68 + r2]);
      *(i32x4*)(Wt + (size_t)(n0 + r2) * DD + k0 + c2 * 8) = u.v;
    }
  } else {                                       // weight product
    const int trL = (z == 3);
    const float* L = trL ? Wfc : Wk;
    const float* R = trL ? Wv : Wq;
    unsigned short* Bt = trL ? BtVF : BtG;
    float* Lsm = Ls;                // [16][68]
    float* Rsm = Ls + 16 * 68;
    const int n0 = blockIdx.x * 64, k0 = blockIdx.y * 64;
    const int tn4 = (t & 15) * 4, tk4 = (t >> 4) * 4;
    float acc[4][4] = {};
    for (int ms = 0; ms < DD; ms += 16) {
      const int lr = t >> 4, lc = (t & 15);
      #pragma unroll
      for (int i = 0; i < 4; ++i) {
        const int nn = lc * 4 + i;
        Lsm[lr * 68 + nn] = trL ? L[(size_t)(ms + lr) * DD + n0 + nn]
                                : L[(size_t)(n0 + nn) * DD + ms + lr];
        Rsm[lr * 68 + nn] = R[(size_t)(k0 + nn) * DD + ms + lr];
      }
      __syncthreads();
      #pragma unroll
      for (int mm = 0; mm < 16; ++mm) {
        float la[4], rb[4];
        #pragma unroll
        for (int i = 0; i < 4; ++i) { la[i] = Lsm[mm * 68 + tn4 + i]; rb[i] = Rsm[mm * 68 + tk4 + i]; }
        #pragma unroll
        for (int i = 0; i < 4; ++i)
          #pragma unroll
          for (int j = 0; j < 4; ++j) acc[i][j] += la[i] * rb[j];
      }
      __syncthreads();
    }
    #pragma unroll
    for (int i = 0; i < 4; ++i)
      #pragma unroll
      for (int j = 0; j < 4; ++j)
        Bt[(size_t)(n0 + tn4 + i) * DD + k0 + tk4 + j] = f2b(acc[i][j]);
  }
}

// v[n] = sum_m Wk[n,m] bq[m];  bvf[n] = sum_m Wfc[m,n] bv[m] + bfc[n]
__global__ __launch_bounds__(640) void wbias(
    const float* __restrict__ Wk, const float* __restrict__ bq,
    const float* __restrict__ Wfc, const float* __restrict__ bv,
    const float* __restrict__ bfc, float* __restrict__ v, float* __restrict__ bvf)
{
  const int t = threadIdx.x;
  if (t < DD) {
    float a = 0.f;
    for (int m = 0; m < DD; ++m) a += Wk[(size_t)t * DD + m] * bq[m];
    v[t] = a;
  } else if (t < 2 * DD) {
    const int n = t - DD;
    float a = 0.f;
    for (int m = 0; m < DD; ++m) a += Wfc[(size_t)m * DD + n] * bv[m];
    bvf[n] = a + bfc[n];
  }
}

// ---------------------------------------------------------------------------
// Per-row LayerNorm + logit (bf16 in), 1 wave/row, merged M=65536.
// ---------------------------------------------------------------------------
__global__ __launch_bounds__(256) void ln_logit(
    const unsigned short* __restrict__ X, const float* __restrict__ gam,
    const float* __restrict__ bet, const float* __restrict__ Wout,
    const float* __restrict__ bout, float* __restrict__ logits, const int M)
{
  const int row = blockIdx.x * 4 + (threadIdx.x >> 6);
  if (row >= M) return;
  const int lane = threadIdx.x & 63;
  const unsigned short* x = X + (size_t)row * DD;
  float v[5]; float s = 0.f;
  #pragma unroll
  for (int i = 0; i < 5; ++i) { v[i] = b2f(x[lane + 64 * i]); s += v[i]; }
  #pragma unroll
  for (int off = 32; off; off >>= 1) s += __shfl_xor(s, off);
  const float mu = s * (1.f / DD);
  float q = 0.f;
  #pragma unroll
  for (int i = 0; i < 5; ++i) { const float d = v[i] - mu; q += d * d; }
  #pragma unroll
  for (int off = 32; off; off >>= 1) q += __shfl_xor(q, off);
  const float inv = rsqrtf(q * (1.f / DD) + LN_EPS);
  float lg = 0.f;
  #pragma unroll
  for (int i = 0; i < 5; ++i) {
    const int k = lane + 64 * i;
    lg += (gam[k] * (v[i] - mu) * inv + bet[k]) * Wout[k];
  }
  #pragma unroll
  for (int off = 32; off; off >>= 1) lg += __shfl_xor(lg, off);
  if (lane == 0) logits[row] = lg + bout[0];
}

// ---------------------------------------------------------------------------
// Final: per-class softmax over logits, weighted mean of P (bf16).
// ---------------------------------------------------------------------------
__global__ __launch_bounds__(320) void final_reduce(
    const float* __restrict__ logits_s, const float* __restrict__ logits_d,
    const unsigned short* __restrict__ Ps, const unsigned short* __restrict__ Pd,
    float* __restrict__ out)
{
  const int c = blockIdx.x;
  const int t = threadIdx.x;
  __shared__ float w[16 + ND];
  __shared__ float red[5];
  if (t < 16) w[t] = logits_s[c * 16 + t];
  for (int j = t; j < ND; j += 320) w[16 + j] = logits_d[c * ND + j];
  __syncthreads();
  if (t == 0) {
    float mx = w[0];
    #pragma unroll
    for (int i = 1; i < 16; ++i) mx = fmaxf(mx, w[i]);
    float ssum = 0.f;
    #pragma unroll
    for (int i = 0; i < 16; ++i) { const float e = __expf(w[i] - mx); w[i] = e; ssum += e; }
    const float inv = 1.f / ssum;
    #pragma unroll
    for (int i = 0; i < 16; ++i) w[i] *= inv;
  }
  float lm = -1e30f;
  for (int j = t; j < ND; j += 320) lm = fmaxf(lm, w[16 + j]);
  #pragma unroll
  for (int off = 32; off; off >>= 1) lm = fmaxf(lm, __shfl_xor(lm, off));
  if ((t & 63) == 0) red[t >> 6] = lm;
  __syncthreads();
  const float mx = fmaxf(fmaxf(fmaxf(red[0], red[1]), fmaxf(red[2], red[3])), red[4]);
  float ls = 0.f;
  for (int j = t; j < ND; j += 320) { const float e = __expf(w[16 + j] - mx); w[16 + j] = e; ls += e; }
  #pragma unroll
  for (int off = 32; off; off >>= 1) ls += __shfl_xor(ls, off);
  __syncthreads();
  if ((t & 63) == 0) red[t >> 6] = ls;
  __syncthreads();
  const float inv = 1.f / (red[0] + red[1] + red[2] + red[3] + red[4]);
  for (int j = t; j < ND; j += 320) w[16 + j] *= inv;
  __syncthreads();
  float acc = 0.f;
  const unsigned short* Psc = Ps + (size_t)c * SHOT * DD + t;
  const unsigned short* Pdc = Pd + (size_t)c * ND * DD + t;
  #pragma unroll 4
  for (int i = 0; i < 16; ++i) acc += w[i] * b2f(Psc[(size_t)i * DD]);
  for (int j = 0; j < ND; ++j) acc += w[16 + j] * b2f(Pdc[(size_t)j * DD]);
  out[c * DD + t] = acc * (1.f / 1024.f);
}

// ---------------------------------------------------------------------------
extern "C" void kernel_launch(void* const* d_in, const int* in_sizes, int n_in,
                              void* d_out, int out_size, void* d_ws, size_t ws_size,
                              hipStream_t stream)
{
  const float* xmean = (const float*)d_in[0];
  const float* x     = (const float*)d_in[1];
  const float* Wsame = (const float*)d_in[2];
  const float* bsame = (const float*)d_in[3];
  const float* Wdiff = (const float*)d_in[4];
  const float* bdiff = (const float*)d_in[5];
  const float* Wq    = (const float*)d_in[6];
  const float* bq    = (const float*)d_in[7];
  const float* Wk    = (const float*)d_in[8];
  const float* bk    = (const float*)d_in[9];   (void)bk; // row-const in softmax
  const float* Wv    = (const float*)d_in[10];
  const float* bv    = (const float*)d_in[11];
  const float* Wfc   = (const float*)d_in[12];
  const float* bfc   = (const float*)d_in[13];
  const float* lng   = (const float*)d_in[14];
  const float* lnb   = (const float*)d_in[15];
  const float* Wout  = (const float*)d_in[16];
  const float* boutp = (const float*)d_in[17];
  float* outp = (float*)d_out;

  char* base = (char*)d_ws;
  size_t off = 0;
  auto alloc = [&](size_t bytes) { char* p = base + off; off += (bytes + 255) & ~(size_t)255; return p; };

  const size_t WB = (size_t)DD * DD * 2;
  unsigned short* BtS  = (unsigned short*)alloc(WB);
  unsigned short* BtD  = (unsigned short*)alloc(WB);
  unsigned short* BtG  = (unsigned short*)alloc(WB);
  unsigned short* BtVF = (unsigned short*)alloc(WB);
  float* vbias = (float*)alloc(DD * 4);
  float* bvf   = (float*)alloc(DD * 4);
  // merged row space: [0,MD) diff (per class 1008), [MD,MT) same (per class 16)
  unsigned short* P_b  = (unsigned short*)alloc((size_t)MT * DD * 2);
  unsigned short* Qg_b = (unsigned short*)alloc((size_t)MT * DD * 2);  // also F out
  unsigned short* O_b  = (unsigned short*)alloc((size_t)MT * DD * 2);
  unsigned short* PtD  = (unsigned short*)alloc((size_t)CC * DD * 1024 * 2);
  unsigned short* PtS  = (unsigned short*)alloc((size_t)CC * DD * 32 * 2);
  float* logits = (float*)alloc((size_t)MT * 4);

  const dim3 blk(256);
  // ---- weight prep (2 dispatches) ----
  wprep<<<dim3(5, 5, 4), blk, 0, stream>>>(Wsame, Wdiff, Wk, Wq, Wfc, Wv,
                                           BtS, BtD, BtG, BtVF);
  wbias<<<dim3(1), dim3(640), 0, stream>>>(Wk, bq, Wfc, bv, bfc, vbias, bvf);

  // ---- P = branch-projected & centered, both branches in one dispatch ----
  const dim3 gAll(MT / 128, 5);
  gemm_mfma<<<gAll, blk, 0, stream>>>(nullptr, x, xmean, 3, BtD, BtS,
                                      bdiff, bsame, P_b, nullptr);
  // ---- P^T for PV (diff: pitch 1024; same: pitch 32) ----
  transpose_p<<<dim3(CC * 16, 5), blk, 0, stream>>>(P_b, PtD, ND, 1024, 16);
  transpose_p<<<dim3(CC, 5), blk, 0, stream>>>(P_b + (size_t)MD * DD, PtS, 16, 32, 1);
  // ---- Qg = P @ G + vbias (merged) ----
  gemm_mfma<<<gAll, blk, 0, stream>>>(P_b, nullptr, nullptr, 0, BtG, nullptr,
                                      vbias, nullptr, Qg_b, nullptr);
  // ---- attention (diff + same) ----
  attn16<<<dim3(CC * 16), blk, 0, stream>>>(Qg_b, P_b, PtD, O_b,
                                            ND, ND, 1024, 32, ND, 16, 63);
  attn16<<<dim3(CC), blk, 0, stream>>>(Qg_b + (size_t)MD * DD, P_b + (size_t)MD * DD,
                                       PtS, O_b + (size_t)MD * DD,
                                       16, 16, 32, 1, 16, 1, 1);
  // ---- F = O @ (Wv Wfc) + bvf + P (merged) ----
  gemm_mfma<<<gAll, blk, 0, stream>>>(O_b, nullptr, nullptr, 0, BtVF, nullptr,
                                      bvf, nullptr, Qg_b, P_b);
  // ---- LN + logits (merged) ----
  ln_logit<<<dim3(MT / 4), blk, 0, stream>>>(Qg_b, lng, lnb, Wout, boutp, logits, MT);
  // ---- final softmax-weighted mean ----
  final_reduce<<<dim3(CC), dim3(320), 0, stream>>>(logits + MD, logits,
                                                   P_b + (size_t)MD * DD, P_b, outp);
}